// Round 4
// baseline (503.847 us; speedup 1.0000x reference)
//
#include <hip/hip_runtime.h>
#include <stdint.h>

typedef unsigned short u16;
typedef unsigned int u32;
using short8 = __attribute__((ext_vector_type(8))) short;   // 8 bf16
using f32x4  = __attribute__((ext_vector_type(4))) float;

#define BDIM 16
#define CDIM 512
#define KLAT 64
#define NTOK 4096

__device__ __forceinline__ u16 f2bf(float x) {
  union { float f; u32 u; } a; a.f = x;
  u32 r = a.u + 0x7FFFu + ((a.u >> 16) & 1u);   // RNE
  return (u16)(r >> 16);
}
__device__ __forceinline__ u32 pack2(float a, float b) {
  return (u32)f2bf(a) | ((u32)f2bf(b) << 16);
}
// order-preserving float->u32 key, and inverse+scale
__device__ __forceinline__ u32 f2key(float x) {
  u32 u = __float_as_uint(x);
  return (u & 0x80000000u) ? ~u : (u | 0x80000000u);
}
__device__ __forceinline__ float keyscale(u32 k_, u32 thr) {
  u32 u = (k_ & 0x80000000u) ? (k_ & 0x7FFFFFFFu) : ~k_;
  float v = __uint_as_float(u);
  return (k_ < thr) ? 0.75f * v : 1.25f * v;
}

// ---------------------------------------------------------------------------
// Setup: w0bf[k][c] = bf16(sum_o lin0[k][o]*conv1[o][c]); b0[k] = lin0[k]·conv1_b;
//        lin1bf[c][k] = bf16(lin1_w[c][k]) (direct cast, layout already K-contig);
//        cw_bf = bf16(conv2_w)
// ---------------------------------------------------------------------------
__global__ __launch_bounds__(256) void k_setup(
    const float* __restrict__ conv1_w, const float* __restrict__ conv1_b,
    const float* __restrict__ lin0_w,  const float* __restrict__ lin1_w,
    const float* __restrict__ conv2_w,
    u16* __restrict__ w0bf, float* __restrict__ b0,
    u16* __restrict__ lin1bf, u16* __restrict__ cwbf)
{
  const int bid = blockIdx.x;
  const int t = threadIdx.x;
  if (bid < 128) {
    // 16 k-blocks(4) x 8 c-blocks(64); lane=c (coalesced conv1 col), k wave-uniform
    const int kb = bid & 15, cb = bid >> 4;
    const int lane = t & 63;
    int k = kb * 4 + (t >> 6);
    k = __builtin_amdgcn_readfirstlane(k);
    const int c = cb * 64 + lane;
    float acc = 0.f;
    const float* l0 = lin0_w + (size_t)k * CDIM;   // scalar loads
    const float* cw = conv1_w + c;
#pragma unroll 4
    for (int o = 0; o < CDIM; ++o)
      acc = fmaf(l0[o], cw[(size_t)o * CDIM], acc);
    w0bf[k * CDIM + c] = f2bf(acc);
  } else if (bid == 128) {
    if (t < KLAT) {
      float acc = 0.f;
      for (int c = 0; c < CDIM; ++c) acc = fmaf(lin0_w[t * CDIM + c], conv1_b[c], acc);
      b0[t] = acc;
    }
  } else if (bid < 193) {
    // conv2_w -> bf16, 65536 float4 over 64 blocks
    const int b2 = bid - 129;
    const float4* src = (const float4*)conv2_w;
#pragma unroll
    for (int i = 0; i < 4; ++i) {
      int idx = (b2 * 256 + t) + i * 16384;
      float4 v = src[idx];
      uint2 o;
      o.x = pack2(v.x, v.y);
      o.y = pack2(v.z, v.w);
      *(uint2*)(cwbf + (size_t)idx * 4) = o;
    }
  } else {
    // lin1_w (512x64 f32, row-major = [c][k], k-contig) -> bf16; 4096 groups of 8
    const int b2 = bid - 193;                 // 0..3
#pragma unroll
    for (int i = 0; i < 4; ++i) {
      int g = b2 * 1024 + i * 256 + t;
      float4 v0 = *(const float4*)(lin1_w + (size_t)g * 8);
      float4 v1 = *(const float4*)(lin1_w + (size_t)g * 8 + 4);
      uint4 o;
      o.x = pack2(v0.x, v0.y); o.y = pack2(v0.z, v0.w);
      o.z = pack2(v1.x, v1.y); o.w = pack2(v1.z, v1.w);
      *(uint4*)(lin1bf + (size_t)g * 8) = o;
    }
  }
}

// ---------------------------------------------------------------------------
// K1 (fused transpose): logits[b][k][n] = sum_c w0[k][c]*x[c][n] + b0[k].
// Reads x[b][c][n] f32 directly; per kc-chunk stages a rotated 64c x 128n
// f32 tile in LDS (mod-32 analog of the proven k_xpose rotation), builds
// B-fragments by 8 scalar LDS reads + in-register bf16 pack. Kills the
// xbt intermediate (saves 134 MB write+read and a whole kernel).
// ---------------------------------------------------------------------------
__global__ __launch_bounds__(256) void k_logits(
    const u16* __restrict__ w0bf, const float* __restrict__ x,
    const float* __restrict__ b0, float* __restrict__ logits)
{
  __shared__ u16 As[64 * 72];             // 9 KiB
  __shared__ float xt[64 * 128];          // 32 KiB rotated f32 tile (c-major)
  const int nb = blockIdx.x, b = blockIdx.y;
  const int t = threadIdx.x;
  const int wv = t >> 6, lane = t & 63;
  const int quad = lane >> 4, l15 = lane & 15;
  f32x4 acc[4][2];
#pragma unroll
  for (int mi = 0; mi < 4; ++mi)
#pragma unroll
    for (int ni = 0; ni < 2; ++ni) acc[mi][ni] = (f32x4){0.f, 0.f, 0.f, 0.f};

  for (int kc = 0; kc < 8; ++kc) {
#pragma unroll
    for (int i = 0; i < 2; ++i) {
      int ch = t + i * 256;               // 512 chunks of 8 bf16 (A: 64x64)
      int row = ch >> 3, col = (ch & 7) * 8;
      uint4 a = *(const uint4*)(w0bf + (size_t)row * CDIM + kc * 64 + col);
      *(uint4*)&As[row * 72 + col] = a;
    }
    // stage x chunk: 64 rows(c) x 32 col4(n); phys4 = (col4+row+(row>>3)) & 31
#pragma unroll
    for (int i = 0; i < 8; ++i) {
      int f4 = t + i * 256;               // 2048 float4
      int row = f4 >> 5, col4 = f4 & 31;
      float4 v = *(const float4*)(x + ((size_t)(b * CDIM + kc * 64 + row)) * NTOK
                                  + nb * 128 + col4 * 4);
      int phys4 = (col4 + row + (row >> 3)) & 31;
      *(float4*)&xt[row * 128 + phys4 * 4] = v;
    }
    __syncthreads();
#pragma unroll
    for (int kk = 0; kk < 2; ++kk) {
      short8 af[4], bf_[2];
#pragma unroll
      for (int mi = 0; mi < 4; ++mi)
        af[mi] = *(short8*)&As[(mi * 16 + l15) * 72 + kk * 32 + quad * 8];
#pragma unroll
      for (int ni = 0; ni < 2; ++ni) {
        const int n = wv * 32 + ni * 16 + l15;       // n_local 0..127
        const int n4 = n >> 2, ns = n & 3;
        union { u32 u[4]; short8 s; } cvt;
#pragma unroll
        for (int jj = 0; jj < 4; ++jj) {
          int ca = kk * 32 + quad * 8 + jj * 2;
          int cb2 = ca + 1;
          float v0 = xt[ca * 128 + (((n4 + ca + (ca >> 3)) & 31) * 4) + ns];
          float v1 = xt[cb2 * 128 + (((n4 + cb2 + (cb2 >> 3)) & 31) * 4) + ns];
          cvt.u[jj] = pack2(v0, v1);
        }
        bf_[ni] = cvt.s;
      }
#pragma unroll
      for (int mi = 0; mi < 4; ++mi)
#pragma unroll
        for (int ni = 0; ni < 2; ++ni)
          acc[mi][ni] = __builtin_amdgcn_mfma_f32_16x16x32_bf16(
              af[mi], bf_[ni], acc[mi][ni], 0, 0, 0);
    }
    __syncthreads();
  }
  // epilogue: + b0[k]   (C/D: col=lane&15, row=quad*4+reg)
#pragma unroll
  for (int mi = 0; mi < 4; ++mi) {
#pragma unroll
    for (int ni = 0; ni < 2; ++ni) {
#pragma unroll
      for (int r = 0; r < 4; ++r) {
        int row = mi * 16 + quad * 4 + r;            // latent k
        int col = nb * 128 + wv * 32 + ni * 16 + l15; // token n
        logits[((size_t)(b * KLAT + row)) * NTOK + col] = acc[mi][ni][r] + b0[row];
      }
    }
  }
}

// ---------------------------------------------------------------------------
// K2: in-place softmax over n (4096) per (b,k) row. 1024 blocks.
// ---------------------------------------------------------------------------
__global__ __launch_bounds__(256) void k_softmax(float* __restrict__ attn)
{
  __shared__ float red[4], red2[4];
  const int t = threadIdx.x;
  float* p = attn + (size_t)blockIdx.x * NTOK;
  float4 v[4];
#pragma unroll
  for (int i = 0; i < 4; ++i) v[i] = ((float4*)p)[t + i * 256];
  float m = v[0].x;
#pragma unroll
  for (int i = 0; i < 4; ++i)
    m = fmaxf(m, fmaxf(fmaxf(v[i].x, v[i].y), fmaxf(v[i].z, v[i].w)));
#pragma unroll
  for (int o = 1; o < 64; o <<= 1) m = fmaxf(m, __shfl_xor(m, o));
  const int wv = t >> 6, lane = t & 63;
  if (lane == 0) red[wv] = m;
  __syncthreads();
  m = fmaxf(fmaxf(red[0], red[1]), fmaxf(red[2], red[3]));
  float s = 0.f;
#pragma unroll
  for (int i = 0; i < 4; ++i) {
    v[i].x = __expf(v[i].x - m); s += v[i].x;
    v[i].y = __expf(v[i].y - m); s += v[i].y;
    v[i].z = __expf(v[i].z - m); s += v[i].z;
    v[i].w = __expf(v[i].w - m); s += v[i].w;
  }
#pragma unroll
  for (int o = 1; o < 64; o <<= 1) s += __shfl_xor(s, o);
  if (lane == 0) red2[wv] = s;
  __syncthreads();
  s = red2[0] + red2[1] + red2[2] + red2[3];
  const float inv = 1.f / s;
#pragma unroll
  for (int i = 0; i < 4; ++i) {
    v[i].x *= inv; v[i].y *= inv; v[i].z *= inv; v[i].w *= inv;
    ((float4*)p)[t + i * 256] = v[i];
  }
}

// ---------------------------------------------------------------------------
// K2b: attnT[b][n][k] = bf16( attn[b][k][n] / (1e-9 + sum_k attn[k][n]) ).
// ---------------------------------------------------------------------------
__global__ __launch_bounds__(256) void k_attnT(
    const float* __restrict__ attn, u16* __restrict__ attnT)
{
  __shared__ float tile[64 * 256];        // 64 KiB, phys4 = (col4 + row + (row>>3)) & 63
  __shared__ float inv_[256];
  const int n0 = blockIdx.x * 256, b = blockIdx.y;
  const int t = threadIdx.x;
#pragma unroll
  for (int i = 0; i < 16; ++i) {
    int f4 = t + i * 256;                 // 4096 float4 = 64 rows(k) x 64 col4(n)
    int row = f4 >> 6, col4 = f4 & 63;
    float4 v = *(const float4*)(attn + ((size_t)(b * KLAT + row)) * NTOK + n0 + col4 * 4);
    int phys4 = (col4 + row + (row >> 3)) & 63;
    *(float4*)&tile[row * 256 + phys4 * 4] = v;
  }
  __syncthreads();
  {
    // per-n column sum over 64 k; thread t owns n = t
    int n4 = t >> 2, sub = t & 3;
    float s = 0.f;
#pragma unroll
    for (int k = 0; k < 64; ++k) {
      int phys4 = (n4 + k + (k >> 3)) & 63;
      s += tile[k * 256 + phys4 * 4 + sub];
    }
    inv_[t] = 1.f / (1e-9f + s);
  }
  __syncthreads();
#pragma unroll
  for (int i = 0; i < 8; ++i) {
    int nr = (t >> 3) + i * 32;
    int cs = (t & 7) * 8;                 // 8 k-groups of 8
    float sc = inv_[nr];
    float w[8];
#pragma unroll
    for (int j = 0; j < 8; ++j) {
      int row = cs + j;
      int phys4 = ((nr >> 2) + row + (row >> 3)) & 63;
      w[j] = tile[row * 256 + phys4 * 4 + (nr & 3)] * sc;
    }
    uint4 o;
    o.x = pack2(w[0], w[1]); o.y = pack2(w[2], w[3]);
    o.z = pack2(w[4], w[5]); o.w = pack2(w[6], w[7]);
    *(uint4*)(attnT + ((size_t)(b * NTOK + n0 + nr)) * KLAT + cs) = o;
  }
}

// ---------------------------------------------------------------------------
// K3: fused lin1 + rank + transpose.  512 threads (8 waves), 64 KiB LDS.
// Phase 2 runs the 4 per-row binary searches INTERLEAVED (shared loop,
// per-row uniform state) -> ~4x ILP on the cmp/ballot/popcount chain.
// ---------------------------------------------------------------------------
__global__ __launch_bounds__(512) void k_lin1rank(
    const u16* __restrict__ lin1bf, const u16* __restrict__ attnT,
    u16* __restrict__ yrt)
{
  __shared__ float tile[32 * 512];        // 64 KiB rotated tile (k_rank layout)
  const int n0 = blockIdx.x * 512, c0 = blockIdx.y * 32, b = blockIdx.z;
  const int t = threadIdx.x;
  const int wv = t >> 6, lane = t & 63;   // wv 0..7
  const int quad = lane >> 4, l15 = lane & 15;

  // ---- phase 1: MFMA  (wave wv owns n-cols [wv*64, +64), all 32 c)
  short8 af[2][2], bfr[4][2];
#pragma unroll
  for (int mi = 0; mi < 2; ++mi)
#pragma unroll
    for (int kk = 0; kk < 2; ++kk)
      af[mi][kk] = *(const short8*)(lin1bf +
          (size_t)(c0 + mi * 16 + l15) * KLAT + kk * 32 + quad * 8);
#pragma unroll
  for (int ni = 0; ni < 4; ++ni)
#pragma unroll
    for (int kk = 0; kk < 2; ++kk)
      bfr[ni][kk] = *(const short8*)(attnT +
          ((size_t)(b * NTOK + n0 + wv * 64 + ni * 16 + l15)) * KLAT + kk * 32 + quad * 8);
  f32x4 acc[2][4];
#pragma unroll
  for (int mi = 0; mi < 2; ++mi)
#pragma unroll
    for (int ni = 0; ni < 4; ++ni) acc[mi][ni] = (f32x4){0.f, 0.f, 0.f, 0.f};
#pragma unroll
  for (int kk = 0; kk < 2; ++kk)
#pragma unroll
    for (int mi = 0; mi < 2; ++mi)
#pragma unroll
      for (int ni = 0; ni < 4; ++ni)
        acc[mi][ni] = __builtin_amdgcn_mfma_f32_16x16x32_bf16(
            af[mi][kk], bfr[ni][kk], acc[mi][ni], 0, 0, 0);
  // acc -> rotated LDS tile (C/D: col=l15 -> n, row=quad*4+r -> c)
#pragma unroll
  for (int mi = 0; mi < 2; ++mi) {
#pragma unroll
    for (int ni = 0; ni < 4; ++ni) {
#pragma unroll
      for (int r = 0; r < 4; ++r) {
        int row = mi * 16 + quad * 4 + r;             // c_local 0..31
        int col = wv * 64 + ni * 16 + l15;            // n_local 0..511
        int phys4 = ((col >> 2) + row + (row >> 3)) & 127;
        tile[row * 512 + phys4 * 4 + (col & 3)] = acc[mi][ni][r];
      }
    }
  }
  __syncthreads();

  // ---- phase 2: rank. wave wv owns rows [wv*4, +4); interleaved search.
  u32 key[4][8];
#pragma unroll
  for (int r = 0; r < 4; ++r) {
    const int row = wv * 4 + r;
    const int rot = row + (row >> 3);
    const int c4a = (lane + rot) & 127;
    const int c4b = (64 + lane + rot) & 127;
    float4 va = *(const float4*)&tile[row * 512 + c4a * 4];
    float4 vb = *(const float4*)&tile[row * 512 + c4b * 4];
    key[r][0] = f2key(va.x); key[r][1] = f2key(va.y);
    key[r][2] = f2key(va.z); key[r][3] = f2key(va.w);
    key[r][4] = f2key(vb.x); key[r][5] = f2key(vb.y);
    key[r][6] = f2key(vb.z); key[r][7] = f2key(vb.w);
  }
  u32 lo[4], hi[4];
#pragma unroll
  for (int r = 0; r < 4; ++r) {
    u32 kmin = key[r][0], kmax = key[r][0];
#pragma unroll
    for (int j = 1; j < 8; ++j) {
      kmin = key[r][j] < kmin ? key[r][j] : kmin;
      kmax = key[r][j] > kmax ? key[r][j] : kmax;
    }
    lo[r] = kmin; hi[r] = kmax;
  }
  // interleaved butterfly min/max (independent chains)
#pragma unroll
  for (int o = 1; o < 64; o <<= 1) {
#pragma unroll
    for (int r = 0; r < 4; ++r) {
      u32 a_ = __shfl_xor(lo[r], o), b_ = __shfl_xor(hi[r], o);
      lo[r] = a_ < lo[r] ? a_ : lo[r];
      hi[r] = b_ > hi[r] ? b_ : hi[r];
    }
  }
  u32 thr[4];
  bool done[4];
#pragma unroll
  for (int r = 0; r < 4; ++r) {
    thr[r] = lo[r];
    done[r] = (lo[r] >= hi[r]);
  }
  // interleaved early-exit binary search (all state wave-uniform)
  for (int it = 0; it < 33; ++it) {
    bool any = false;
    u32 mid[4];
#pragma unroll
    for (int r = 0; r < 4; ++r) {
      if (!done[r]) {
        any = true;
        u32 d = hi[r] - lo[r];
        mid[r] = lo[r] + (d >> 1) + (d & 1u);
      }
    }
    if (!any) break;
    int cnt[4];
#pragma unroll
    for (int r = 0; r < 4; ++r) {
      if (!done[r]) {
        int c = 0;
#pragma unroll
        for (int j = 0; j < 8; ++j)
          c += (int)__popcll(__ballot(key[r][j] >= mid[r]));
        cnt[r] = c;
      }
    }
#pragma unroll
    for (int r = 0; r < 4; ++r) {
      if (!done[r]) {
        if (cnt[r] == 256) { thr[r] = mid[r]; done[r] = true; }
        else {
          if (cnt[r] > 256) lo[r] = mid[r]; else hi[r] = mid[r] - 1u;
          if (lo[r] >= hi[r]) { thr[r] = lo[r]; done[r] = true; }
        }
      }
    }
  }
  // scale + write back
#pragma unroll
  for (int r = 0; r < 4; ++r) {
    const int row = wv * 4 + r;
    const int rot = row + (row >> 3);
    const int c4a = (lane + rot) & 127;
    const int c4b = (64 + lane + rot) & 127;
    float4 oa, ob;
    oa.x = keyscale(key[r][0], thr[r]); oa.y = keyscale(key[r][1], thr[r]);
    oa.z = keyscale(key[r][2], thr[r]); oa.w = keyscale(key[r][3], thr[r]);
    ob.x = keyscale(key[r][4], thr[r]); ob.y = keyscale(key[r][5], thr[r]);
    ob.z = keyscale(key[r][6], thr[r]); ob.w = keyscale(key[r][7], thr[r]);
    *(float4*)&tile[row * 512 + c4a * 4] = oa;
    *(float4*)&tile[row * 512 + c4b * 4] = ob;
  }
  __syncthreads();

  // ---- phase 3: transposed bf16 write yrt[b][n][c]  (512 threads, 4 iters)
#pragma unroll
  for (int i = 0; i < 4; ++i) {
    int nr = (t >> 2) + i * 128;
    int cs = (t & 3) * 8;
    float w[8];
#pragma unroll
    for (int j = 0; j < 8; ++j) {
      int row = cs + j;
      int phys4 = ((nr >> 2) + row + (row >> 3)) & 127;
      w[j] = tile[row * 512 + phys4 * 4 + (nr & 3)];
    }
    uint4 o;
    o.x = pack2(w[0], w[1]); o.y = pack2(w[2], w[3]);
    o.z = pack2(w[4], w[5]); o.w = pack2(w[6], w[7]);
    *(uint4*)(yrt + ((size_t)(b * NTOK + n0 + nr)) * CDIM + c0 + cs) = o;
  }
}

// ---------------------------------------------------------------------------
// K5: out = relu(relu(conv2_w @ yr) + x).  bf16 MFMA 16x16x32, 128x128 tile,
// BK=64, 4 waves each 64x64. A = cw_bf [o][c], B = yr^T [n][c] (both K-contig).
// ---------------------------------------------------------------------------
__global__ __launch_bounds__(256) void k_conv2(
    const u16* __restrict__ cwbf, const u16* __restrict__ yrt,
    const float* __restrict__ x, float* __restrict__ out)
{
  __shared__ u16 As[128 * 72];            // pitch 72 bf16 (pad 8) -> 144B rows
  __shared__ u16 Bs[128 * 72];
  const int nb = blockIdx.x, mb = blockIdx.y, b = blockIdx.z;
  const int t = threadIdx.x;
  const int wv = t >> 6, lane = t & 63;
  const int wm = wv >> 1, wn = wv & 1;
  const int quad = lane >> 4, l15 = lane & 15;
  f32x4 acc[4][4];
#pragma unroll
  for (int mi = 0; mi < 4; ++mi)
#pragma unroll
    for (int ni = 0; ni < 4; ++ni) acc[mi][ni] = (f32x4){0.f, 0.f, 0.f, 0.f};

  for (int kc = 0; kc < 8; ++kc) {
#pragma unroll
    for (int i = 0; i < 4; ++i) {
      int ch = t + i * 256;               // 1024 chunks of 8 bf16
      int row = ch >> 3, col = (ch & 7) * 8;
      uint4 a = *(const uint4*)(cwbf + ((size_t)(mb * 128 + row)) * CDIM + kc * 64 + col);
      *(uint4*)&As[row * 72 + col] = a;
      uint4 bb = *(const uint4*)(yrt + ((size_t)(b * NTOK + nb * 128 + row)) * CDIM + kc * 64 + col);
      *(uint4*)&Bs[row * 72 + col] = bb;
    }
    __syncthreads();
#pragma unroll
    for (int kk = 0; kk < 2; ++kk) {
      short8 af[4], bf_[4];
#pragma unroll
      for (int mi = 0; mi < 4; ++mi)
        af[mi] = *(short8*)&As[(wm * 64 + mi * 16 + l15) * 72 + kk * 32 + quad * 8];
#pragma unroll
      for (int ni = 0; ni < 4; ++ni)
        bf_[ni] = *(short8*)&Bs[(wn * 64 + ni * 16 + l15) * 72 + kk * 32 + quad * 8];
#pragma unroll
      for (int mi = 0; mi < 4; ++mi)
#pragma unroll
        for (int ni = 0; ni < 4; ++ni)
          acc[mi][ni] = __builtin_amdgcn_mfma_f32_16x16x32_bf16(
              af[mi], bf_[ni], acc[mi][ni], 0, 0, 0);
    }
    __syncthreads();
  }
  // epilogue: relu -> +x -> relu   (C/D layout: col=lane&15, row=quad*4+reg)
#pragma unroll
  for (int mi = 0; mi < 4; ++mi) {
#pragma unroll
    for (int ni = 0; ni < 4; ++ni) {
#pragma unroll
      for (int r = 0; r < 4; ++r) {
        int row = mb * 128 + wm * 64 + mi * 16 + quad * 4 + r;
        int col = nb * 128 + wn * 64 + ni * 16 + l15;
        size_t off = ((size_t)(b * CDIM + row)) * NTOK + col;
        float g = fmaxf(acc[mi][ni][r], 0.f) + x[off];
        out[off] = fmaxf(g, 0.f);
      }
    }
  }
}

// ---------------------------------------------------------------------------
extern "C" void kernel_launch(void* const* d_in, const int* in_sizes, int n_in,
                              void* d_out, int out_size, void* d_ws, size_t ws_size,
                              hipStream_t stream)
{
  const float* x       = (const float*)d_in[0];
  const float* conv1_w = (const float*)d_in[1];
  const float* conv1_b = (const float*)d_in[2];
  const float* lin0_w  = (const float*)d_in[3];
  const float* lin1_w  = (const float*)d_in[4];
  const float* conv2_w = (const float*)d_in[5];
  float* out = (float*)d_out;

  char* ws = (char*)d_ws;
  float* attn  = (float*)ws;                               // 16,777,216 B
  u16*   yrt   = (u16*)(ws + 16777216);                    // 67,108,864 B (k_lin1rank -> k_conv2)
  u16*   attnT = (u16*)d_out;                              // 8,388,608 B in d_out (free until
                                                           // k_conv2 writes out) -- must NOT
                                                           // alias yrt (read+write in k_lin1rank)
  char*  wsm   = ws + 16777216 + 67108864;
  u16*   w0bf  = (u16*)wsm;                                // 65,536 B (slot 131072)
  float* b0    = (float*)(wsm + 131072);                   // 256 B
  u16*   lin1bf= (u16*)(wsm + 131328);                     // 65,536 B (slot 131072)
  u16*   cwbf  = (u16*)(wsm + 262400);                     // 524,288 B

  k_setup   <<<197, 256, 0, stream>>>(conv1_w, conv1_b, lin0_w, lin1_w, conv2_w,
                                      w0bf, b0, lin1bf, cwbf);
  k_logits  <<<dim3(32, 16), 256, 0, stream>>>(w0bf, x, b0, attn);
  k_softmax <<<1024, 256, 0, stream>>>(attn);
  k_attnT   <<<dim3(16, 16), 256, 0, stream>>>(attn, attnT);
  k_lin1rank<<<dim3(8, 16, 16), 512, 0, stream>>>(lin1bf, attnT, yrt);
  k_conv2   <<<dim3(32, 4, 16), 256, 0, stream>>>(cwbf, yrt, x, out);
}

// Round 6
// 477.328 us; speedup vs baseline: 1.0556x; 1.0556x over previous
//
#include <hip/hip_runtime.h>
#include <stdint.h>

typedef unsigned short u16;
typedef unsigned int u32;
using short8 = __attribute__((ext_vector_type(8))) short;   // 8 bf16
using f32x4  = __attribute__((ext_vector_type(4))) float;

#define BDIM 16
#define CDIM 512
#define KLAT 64
#define NTOK 4096

__device__ __forceinline__ u16 f2bf(float x) {
  union { float f; u32 u; } a; a.f = x;
  u32 r = a.u + 0x7FFFu + ((a.u >> 16) & 1u);   // RNE
  return (u16)(r >> 16);
}
__device__ __forceinline__ u32 pack2(float a, float b) {
  return (u32)f2bf(a) | ((u32)f2bf(b) << 16);
}
// order-preserving float->u32 key, and inverse+scale
__device__ __forceinline__ u32 f2key(float x) {
  u32 u = __float_as_uint(x);
  return (u & 0x80000000u) ? ~u : (u | 0x80000000u);
}
__device__ __forceinline__ float keyscale(u32 k_, u32 thr) {
  u32 u = (k_ & 0x80000000u) ? (k_ & 0x7FFFFFFFu) : ~k_;
  float v = __uint_as_float(u);
  return (k_ < thr) ? 0.75f * v : 1.25f * v;
}
// async 16B global->LDS copy (dest = wave-uniform base + lane*16)
__device__ __forceinline__ void gload_lds16(const void* g, void* l) {
  __builtin_amdgcn_global_load_lds(
      (const __attribute__((address_space(1))) unsigned int*)g,
      (__attribute__((address_space(3))) unsigned int*)l, 16, 0, 0);
}

// ---------------------------------------------------------------------------
// Setup: w0bf[k][c] = bf16(sum_o lin0[k][o]*conv1[o][c]); b0[k] = lin0[k]·conv1_b;
//        lin1bf[c][k] = bf16(lin1_w[c][k]) (direct cast, layout already K-contig);
//        cw_bf = bf16(conv2_w)
// ---------------------------------------------------------------------------
__global__ __launch_bounds__(256) void k_setup(
    const float* __restrict__ conv1_w, const float* __restrict__ conv1_b,
    const float* __restrict__ lin0_w,  const float* __restrict__ lin1_w,
    const float* __restrict__ conv2_w,
    u16* __restrict__ w0bf, float* __restrict__ b0,
    u16* __restrict__ lin1bf, u16* __restrict__ cwbf)
{
  const int bid = blockIdx.x;
  const int t = threadIdx.x;
  if (bid < 128) {
    // 16 k-blocks(4) x 8 c-blocks(64); lane=c (coalesced conv1 col), k wave-uniform
    const int kb = bid & 15, cb = bid >> 4;
    const int lane = t & 63;
    int k = kb * 4 + (t >> 6);
    k = __builtin_amdgcn_readfirstlane(k);
    const int c = cb * 64 + lane;
    float acc = 0.f;
    const float* l0 = lin0_w + (size_t)k * CDIM;   // scalar loads
    const float* cw = conv1_w + c;
#pragma unroll 4
    for (int o = 0; o < CDIM; ++o)
      acc = fmaf(l0[o], cw[(size_t)o * CDIM], acc);
    w0bf[k * CDIM + c] = f2bf(acc);
  } else if (bid == 128) {
    if (t < KLAT) {
      float acc = 0.f;
      for (int c = 0; c < CDIM; ++c) acc = fmaf(lin0_w[t * CDIM + c], conv1_b[c], acc);
      b0[t] = acc;
    }
  } else if (bid < 193) {
    // conv2_w -> bf16, 65536 float4 over 64 blocks
    const int b2 = bid - 129;
    const float4* src = (const float4*)conv2_w;
#pragma unroll
    for (int i = 0; i < 4; ++i) {
      int idx = (b2 * 256 + t) + i * 16384;
      float4 v = src[idx];
      uint2 o;
      o.x = pack2(v.x, v.y);
      o.y = pack2(v.z, v.w);
      *(uint2*)(cwbf + (size_t)idx * 4) = o;
    }
  } else {
    // lin1_w (512x64 f32, row-major = [c][k], k-contig) -> bf16; 4096 groups of 8
    const int b2 = bid - 193;                 // 0..3
#pragma unroll
    for (int i = 0; i < 4; ++i) {
      int g = b2 * 1024 + i * 256 + t;
      float4 v0 = *(const float4*)(lin1_w + (size_t)g * 8);
      float4 v1 = *(const float4*)(lin1_w + (size_t)g * 8 + 4);
      uint4 o;
      o.x = pack2(v0.x, v0.y); o.y = pack2(v0.z, v0.w);
      o.z = pack2(v1.x, v1.y); o.w = pack2(v1.z, v1.w);
      *(uint4*)(lin1bf + (size_t)g * 8) = o;
    }
  }
}

// ---------------------------------------------------------------------------
// K1 (fused transpose): logits[b][k][n] = sum_c w0[k][c]*x[c][n] + b0[k].
// Reads x[b][c][n] f32 directly; per kc-chunk stages a rotated 64c x 128n
// f32 tile in LDS, builds B-fragments by 8 scalar LDS reads + bf16 pack.
// ---------------------------------------------------------------------------
__global__ __launch_bounds__(256) void k_logits(
    const u16* __restrict__ w0bf, const float* __restrict__ x,
    const float* __restrict__ b0, float* __restrict__ logits)
{
  __shared__ u16 As[64 * 72];             // 9 KiB
  __shared__ float xt[64 * 128];          // 32 KiB rotated f32 tile (c-major)
  const int nb = blockIdx.x, b = blockIdx.y;
  const int t = threadIdx.x;
  const int wv = t >> 6, lane = t & 63;
  const int quad = lane >> 4, l15 = lane & 15;
  f32x4 acc[4][2];
#pragma unroll
  for (int mi = 0; mi < 4; ++mi)
#pragma unroll
    for (int ni = 0; ni < 2; ++ni) acc[mi][ni] = (f32x4){0.f, 0.f, 0.f, 0.f};

  for (int kc = 0; kc < 8; ++kc) {
#pragma unroll
    for (int i = 0; i < 2; ++i) {
      int ch = t + i * 256;               // 512 chunks of 8 bf16 (A: 64x64)
      int row = ch >> 3, col = (ch & 7) * 8;
      uint4 a = *(const uint4*)(w0bf + (size_t)row * CDIM + kc * 64 + col);
      *(uint4*)&As[row * 72 + col] = a;
    }
    // stage x chunk: 64 rows(c) x 32 col4(n); phys4 = (col4+row+(row>>3)) & 31
#pragma unroll
    for (int i = 0; i < 8; ++i) {
      int f4 = t + i * 256;               // 2048 float4
      int row = f4 >> 5, col4 = f4 & 31;
      float4 v = *(const float4*)(x + ((size_t)(b * CDIM + kc * 64 + row)) * NTOK
                                  + nb * 128 + col4 * 4);
      int phys4 = (col4 + row + (row >> 3)) & 31;
      *(float4*)&xt[row * 128 + phys4 * 4] = v;
    }
    __syncthreads();
#pragma unroll
    for (int kk = 0; kk < 2; ++kk) {
      short8 af[4], bf_[2];
#pragma unroll
      for (int mi = 0; mi < 4; ++mi)
        af[mi] = *(short8*)&As[(mi * 16 + l15) * 72 + kk * 32 + quad * 8];
#pragma unroll
      for (int ni = 0; ni < 2; ++ni) {
        const int n = wv * 32 + ni * 16 + l15;       // n_local 0..127
        const int n4 = n >> 2, ns = n & 3;
        union { u32 u[4]; short8 s; } cvt;
#pragma unroll
        for (int jj = 0; jj < 4; ++jj) {
          int ca = kk * 32 + quad * 8 + jj * 2;
          int cb2 = ca + 1;
          float v0 = xt[ca * 128 + (((n4 + ca + (ca >> 3)) & 31) * 4) + ns];
          float v1 = xt[cb2 * 128 + (((n4 + cb2 + (cb2 >> 3)) & 31) * 4) + ns];
          cvt.u[jj] = pack2(v0, v1);
        }
        bf_[ni] = cvt.s;
      }
#pragma unroll
      for (int mi = 0; mi < 4; ++mi)
#pragma unroll
        for (int ni = 0; ni < 2; ++ni)
          acc[mi][ni] = __builtin_amdgcn_mfma_f32_16x16x32_bf16(
              af[mi], bf_[ni], acc[mi][ni], 0, 0, 0);
    }
    __syncthreads();
  }
  // epilogue: + b0[k]   (C/D: col=lane&15, row=quad*4+reg)
#pragma unroll
  for (int mi = 0; mi < 4; ++mi) {
#pragma unroll
    for (int ni = 0; ni < 2; ++ni) {
#pragma unroll
      for (int r = 0; r < 4; ++r) {
        int row = mi * 16 + quad * 4 + r;            // latent k
        int col = nb * 128 + wv * 32 + ni * 16 + l15; // token n
        logits[((size_t)(b * KLAT + row)) * NTOK + col] = acc[mi][ni][r] + b0[row];
      }
    }
  }
}

// ---------------------------------------------------------------------------
// K2: in-place softmax over n (4096) per (b,k) row. 1024 blocks.
// ---------------------------------------------------------------------------
__global__ __launch_bounds__(256) void k_softmax(float* __restrict__ attn)
{
  __shared__ float red[4], red2[4];
  const int t = threadIdx.x;
  float* p = attn + (size_t)blockIdx.x * NTOK;
  float4 v[4];
#pragma unroll
  for (int i = 0; i < 4; ++i) v[i] = ((float4*)p)[t + i * 256];
  float m = v[0].x;
#pragma unroll
  for (int i = 0; i < 4; ++i)
    m = fmaxf(m, fmaxf(fmaxf(v[i].x, v[i].y), fmaxf(v[i].z, v[i].w)));
#pragma unroll
  for (int o = 1; o < 64; o <<= 1) m = fmaxf(m, __shfl_xor(m, o));
  const int wv = t >> 6, lane = t & 63;
  if (lane == 0) red[wv] = m;
  __syncthreads();
  m = fmaxf(fmaxf(red[0], red[1]), fmaxf(red[2], red[3]));
  float s = 0.f;
#pragma unroll
  for (int i = 0; i < 4; ++i) {
    v[i].x = __expf(v[i].x - m); s += v[i].x;
    v[i].y = __expf(v[i].y - m); s += v[i].y;
    v[i].z = __expf(v[i].z - m); s += v[i].z;
    v[i].w = __expf(v[i].w - m); s += v[i].w;
  }
#pragma unroll
  for (int o = 1; o < 64; o <<= 1) s += __shfl_xor(s, o);
  if (lane == 0) red2[wv] = s;
  __syncthreads();
  s = red2[0] + red2[1] + red2[2] + red2[3];
  const float inv = 1.f / s;
#pragma unroll
  for (int i = 0; i < 4; ++i) {
    v[i].x *= inv; v[i].y *= inv; v[i].z *= inv; v[i].w *= inv;
    ((float4*)p)[t + i * 256] = v[i];
  }
}

// ---------------------------------------------------------------------------
// K2b: attnT[b][n][k] = bf16( attn[b][k][n] / (1e-9 + sum_k attn[k][n]) ).
// ---------------------------------------------------------------------------
__global__ __launch_bounds__(256) void k_attnT(
    const float* __restrict__ attn, u16* __restrict__ attnT)
{
  __shared__ float tile[64 * 256];        // 64 KiB, phys4 = (col4 + row + (row>>3)) & 63
  __shared__ float inv_[256];
  const int n0 = blockIdx.x * 256, b = blockIdx.y;
  const int t = threadIdx.x;
#pragma unroll
  for (int i = 0; i < 16; ++i) {
    int f4 = t + i * 256;                 // 4096 float4 = 64 rows(k) x 64 col4(n)
    int row = f4 >> 6, col4 = f4 & 63;
    float4 v = *(const float4*)(attn + ((size_t)(b * KLAT + row)) * NTOK + n0 + col4 * 4);
    int phys4 = (col4 + row + (row >> 3)) & 63;
    *(float4*)&tile[row * 256 + phys4 * 4] = v;
  }
  __syncthreads();
  {
    // per-n column sum over 64 k; thread t owns n = t
    int n4 = t >> 2, sub = t & 3;
    float s = 0.f;
#pragma unroll
    for (int k = 0; k < 64; ++k) {
      int phys4 = (n4 + k + (k >> 3)) & 63;
      s += tile[k * 256 + phys4 * 4 + sub];
    }
    inv_[t] = 1.f / (1e-9f + s);
  }
  __syncthreads();
#pragma unroll
  for (int i = 0; i < 8; ++i) {
    int nr = (t >> 3) + i * 32;
    int cs = (t & 7) * 8;                 // 8 k-groups of 8
    float sc = inv_[nr];
    float w[8];
#pragma unroll
    for (int j = 0; j < 8; ++j) {
      int row = cs + j;
      int phys4 = ((nr >> 2) + row + (row >> 3)) & 63;
      w[j] = tile[row * 256 + phys4 * 4 + (nr & 3)] * sc;
    }
    uint4 o;
    o.x = pack2(w[0], w[1]); o.y = pack2(w[2], w[3]);
    o.z = pack2(w[4], w[5]); o.w = pack2(w[6], w[7]);
    *(uint4*)(attnT + ((size_t)(b * NTOK + n0 + nr)) * KLAT + cs) = o;
  }
}

// ---------------------------------------------------------------------------
// K3: fused lin1 + rank + transpose.  512 threads (8 waves), 64 KiB LDS.
// Phase 2: per-row SEQUENTIAL early-exit binary search (proven R3 form --
// the interleaved variant regressed: max-convergence coupling + branch
// overhead around every ballot group).
// ---------------------------------------------------------------------------
__global__ __launch_bounds__(512) void k_lin1rank(
    const u16* __restrict__ lin1bf, const u16* __restrict__ attnT,
    u16* __restrict__ yrt)
{
  __shared__ float tile[32 * 512];        // 64 KiB rotated tile (k_rank layout)
  const int n0 = blockIdx.x * 512, c0 = blockIdx.y * 32, b = blockIdx.z;
  const int t = threadIdx.x;
  const int wv = t >> 6, lane = t & 63;   // wv 0..7
  const int quad = lane >> 4, l15 = lane & 15;

  // ---- phase 1: MFMA  (wave wv owns n-cols [wv*64, +64), all 32 c)
  short8 af[2][2], bfr[4][2];
#pragma unroll
  for (int mi = 0; mi < 2; ++mi)
#pragma unroll
    for (int kk = 0; kk < 2; ++kk)
      af[mi][kk] = *(const short8*)(lin1bf +
          (size_t)(c0 + mi * 16 + l15) * KLAT + kk * 32 + quad * 8);
#pragma unroll
  for (int ni = 0; ni < 4; ++ni)
#pragma unroll
    for (int kk = 0; kk < 2; ++kk)
      bfr[ni][kk] = *(const short8*)(attnT +
          ((size_t)(b * NTOK + n0 + wv * 64 + ni * 16 + l15)) * KLAT + kk * 32 + quad * 8);
  f32x4 acc[2][4];
#pragma unroll
  for (int mi = 0; mi < 2; ++mi)
#pragma unroll
    for (int ni = 0; ni < 4; ++ni) acc[mi][ni] = (f32x4){0.f, 0.f, 0.f, 0.f};
#pragma unroll
  for (int kk = 0; kk < 2; ++kk)
#pragma unroll
    for (int mi = 0; mi < 2; ++mi)
#pragma unroll
      for (int ni = 0; ni < 4; ++ni)
        acc[mi][ni] = __builtin_amdgcn_mfma_f32_16x16x32_bf16(
            af[mi][kk], bfr[ni][kk], acc[mi][ni], 0, 0, 0);
  // acc -> rotated LDS tile (C/D: col=l15 -> n, row=quad*4+r -> c)
#pragma unroll
  for (int mi = 0; mi < 2; ++mi) {
#pragma unroll
    for (int ni = 0; ni < 4; ++ni) {
#pragma unroll
      for (int r = 0; r < 4; ++r) {
        int row = mi * 16 + quad * 4 + r;             // c_local 0..31
        int col = wv * 64 + ni * 16 + l15;            // n_local 0..511
        int phys4 = ((col >> 2) + row + (row >> 3)) & 127;
        tile[row * 512 + phys4 * 4 + (col & 3)] = acc[mi][ni][r];
      }
    }
  }
  __syncthreads();

  // ---- phase 2: rank. wave wv owns rows [wv*4, +4); sequential per row.
#pragma unroll
  for (int r = 0; r < 4; ++r) {
    const int row = wv * 4 + r;
    const int rot = row + (row >> 3);
    const int c4a = (lane + rot) & 127;          // logical col4 = lane
    const int c4b = (64 + lane + rot) & 127;     // logical col4 = 64 + lane
    float* pa = &tile[row * 512 + c4a * 4];
    float* pb = &tile[row * 512 + c4b * 4];
    float4 va = *(const float4*)pa;
    float4 vb = *(const float4*)pb;
    u32 key[8];
    key[0] = f2key(va.x); key[1] = f2key(va.y);
    key[2] = f2key(va.z); key[3] = f2key(va.w);
    key[4] = f2key(vb.x); key[5] = f2key(vb.y);
    key[6] = f2key(vb.z); key[7] = f2key(vb.w);
    // seed [lo,hi] with the row's key range (butterfly min/max)
    u32 kmin = key[0], kmax = key[0];
#pragma unroll
    for (int j = 1; j < 8; ++j) {
      kmin = key[j] < kmin ? key[j] : kmin;
      kmax = key[j] > kmax ? key[j] : kmax;
    }
#pragma unroll
    for (int o = 1; o < 64; o <<= 1) {
      u32 a_ = __shfl_xor(kmin, o), b_ = __shfl_xor(kmax, o);
      kmin = a_ < kmin ? a_ : kmin;
      kmax = b_ > kmax ? b_ : kmax;
    }
    // early-exit binary search: exact 256th-largest classification
    u32 lo = kmin, hi = kmax;
    u32 thr;
    if (lo >= hi) thr = lo;
    else for (;;) {
      u32 d = hi - lo;
      u32 mid = lo + (d >> 1) + (d & 1u);
      int cnt = 0;
#pragma unroll
      for (int j = 0; j < 8; ++j)
        cnt += (int)__popcll(__ballot(key[j] >= mid));
      if (cnt == 256) { thr = mid; break; }   // mid in (v257, v256]: exact classes
      if (cnt > 256) lo = mid; else hi = mid - 1u;
      if (lo >= hi) { thr = lo; break; }      // exact v256 (duplicate-safe)
    }
    float4 oa, ob;
    oa.x = keyscale(key[0], thr); oa.y = keyscale(key[1], thr);
    oa.z = keyscale(key[2], thr); oa.w = keyscale(key[3], thr);
    ob.x = keyscale(key[4], thr); ob.y = keyscale(key[5], thr);
    ob.z = keyscale(key[6], thr); ob.w = keyscale(key[7], thr);
    *(float4*)pa = oa;
    *(float4*)pb = ob;
  }
  __syncthreads();

  // ---- phase 3: transposed bf16 write yrt[b][n][c]  (512 threads, 4 iters)
#pragma unroll
  for (int i = 0; i < 4; ++i) {
    int nr = (t >> 2) + i * 128;
    int cs = (t & 3) * 8;
    float w[8];
#pragma unroll
    for (int j = 0; j < 8; ++j) {
      int row = cs + j;
      int phys4 = ((nr >> 2) + row + (row >> 3)) & 127;
      w[j] = tile[row * 512 + phys4 * 4 + (nr & 3)];
    }
    uint4 o;
    o.x = pack2(w[0], w[1]); o.y = pack2(w[2], w[3]);
    o.z = pack2(w[4], w[5]); o.w = pack2(w[6], w[7]);
    *(uint4*)(yrt + ((size_t)(b * NTOK + n0 + nr)) * CDIM + c0 + cs) = o;
  }
}

// ---------------------------------------------------------------------------
// K5: out = relu(relu(conv2_w @ yr) + x).  bf16 MFMA 16x16x32, 128x128 tile,
// BK=64, 4 waves each 64x64.  Staging via global_load_lds (16B) into LINEAR
// 128B rows with XOR-granule swizzle: LDS slot g of row r holds global
// granule g^(r&7) (inverse-swizzled per-lane SOURCE addr, rule both-sides);
// fragment reads use granule (kk*4+quad)^(row&7).  Banks load uniformly.
// ---------------------------------------------------------------------------
__global__ __launch_bounds__(256) void k_conv2(
    const u16* __restrict__ cwbf, const u16* __restrict__ yrt,
    const float* __restrict__ x, float* __restrict__ out)
{
  __shared__ __align__(16) u16 As[128 * 64];   // 16 KiB, linear 128B rows (swizzled content)
  __shared__ __align__(16) u16 Bs[128 * 64];   // 16 KiB
  const int nb = blockIdx.x, mb = blockIdx.y, b = blockIdx.z;
  const int t = threadIdx.x;
  const int wv = t >> 6, lane = t & 63;
  const int wm = wv >> 1, wn = wv & 1;
  const int quad = lane >> 4, l15 = lane & 15;
  const int lrow = lane >> 3, lg = lane & 7;   // staging: lane -> (row-in-8, granule)
  f32x4 acc[4][4];
#pragma unroll
  for (int mi = 0; mi < 4; ++mi)
#pragma unroll
    for (int ni = 0; ni < 4; ++ni) acc[mi][ni] = (f32x4){0.f, 0.f, 0.f, 0.f};

  for (int kc = 0; kc < 8; ++kc) {
#pragma unroll
    for (int i = 0; i < 4; ++i) {
      const int r0 = i * 32 + wv * 8;           // wave-uniform row base (8 rows/call)
      const int row = r0 + lrow;
      const int gsrc = lg ^ (row & 7);          // inverse-swizzled source granule
      const u16* ga = cwbf + ((size_t)(mb * 128 + row)) * CDIM + kc * 64 + gsrc * 8;
      gload_lds16(ga, &As[r0 * 64]);
      const u16* gb = yrt + ((size_t)(b * NTOK + nb * 128 + row)) * CDIM + kc * 64 + gsrc * 8;
      gload_lds16(gb, &Bs[r0 * 64]);
    }
    __syncthreads();
#pragma unroll
    for (int kk = 0; kk < 2; ++kk) {
      short8 af[4], bf_[4];
#pragma unroll
      for (int mi = 0; mi < 4; ++mi) {
        int row = wm * 64 + mi * 16 + l15;
        int q = kk * 4 + quad;
        af[mi] = *(short8*)&As[row * 64 + ((q ^ (row & 7)) * 8)];
      }
#pragma unroll
      for (int ni = 0; ni < 4; ++ni) {
        int row = wn * 64 + ni * 16 + l15;
        int q = kk * 4 + quad;
        bf_[ni] = *(short8*)&Bs[row * 64 + ((q ^ (row & 7)) * 8)];
      }
#pragma unroll
      for (int mi = 0; mi < 4; ++mi)
#pragma unroll
        for (int ni = 0; ni < 4; ++ni)
          acc[mi][ni] = __builtin_amdgcn_mfma_f32_16x16x32_bf16(
              af[mi], bf_[ni], acc[mi][ni], 0, 0, 0);
    }
    __syncthreads();
  }
  // epilogue: relu -> +x -> relu   (C/D layout: col=lane&15, row=quad*4+reg)
#pragma unroll
  for (int mi = 0; mi < 4; ++mi) {
#pragma unroll
    for (int ni = 0; ni < 4; ++ni) {
#pragma unroll
      for (int r = 0; r < 4; ++r) {
        int row = mb * 128 + wm * 64 + mi * 16 + quad * 4 + r;
        int col = nb * 128 + wn * 64 + ni * 16 + l15;
        size_t off = ((size_t)(b * CDIM + row)) * NTOK + col;
        float g = fmaxf(acc[mi][ni][r], 0.f) + x[off];
        out[off] = fmaxf(g, 0.f);
      }
    }
  }
}

// ---------------------------------------------------------------------------
extern "C" void kernel_launch(void* const* d_in, const int* in_sizes, int n_in,
                              void* d_out, int out_size, void* d_ws, size_t ws_size,
                              hipStream_t stream)
{
  const float* x       = (const float*)d_in[0];
  const float* conv1_w = (const float*)d_in[1];
  const float* conv1_b = (const float*)d_in[2];
  const float* lin0_w  = (const float*)d_in[3];
  const float* lin1_w  = (const float*)d_in[4];
  const float* conv2_w = (const float*)d_in[5];
  float* out = (float*)d_out;

  char* ws = (char*)d_ws;
  float* attn  = (float*)ws;                               // 16,777,216 B
  u16*   yrt   = (u16*)(ws + 16777216);                    // 67,108,864 B (k_lin1rank -> k_conv2)
  u16*   attnT = (u16*)d_out;                              // 8,388,608 B in d_out (free until
                                                           // k_conv2 writes out) -- must NOT
                                                           // alias yrt (read+write in k_lin1rank)
  char*  wsm   = ws + 16777216 + 67108864;
  u16*   w0bf  = (u16*)wsm;                                // 65,536 B (slot 131072)
  float* b0    = (float*)(wsm + 131072);                   // 256 B
  u16*   lin1bf= (u16*)(wsm + 131328);                     // 65,536 B (slot 131072)
  u16*   cwbf  = (u16*)(wsm + 262400);                     // 524,288 B

  k_setup   <<<197, 256, 0, stream>>>(conv1_w, conv1_b, lin0_w, lin1_w, conv2_w,
                                      w0bf, b0, lin1bf, cwbf);
  k_logits  <<<dim3(32, 16), 256, 0, stream>>>(w0bf, x, b0, attn);
  k_softmax <<<1024, 256, 0, stream>>>(attn);
  k_attnT   <<<dim3(16, 16), 256, 0, stream>>>(attn, attnT);
  k_lin1rank<<<dim3(8, 16, 16), 512, 0, stream>>>(lin1bf, attnT, yrt);
  k_conv2   <<<dim3(32, 4, 16), 256, 0, stream>>>(cwbf, yrt, x, out);
}

// Round 7
// 473.965 us; speedup vs baseline: 1.0630x; 1.0071x over previous
//
#include <hip/hip_runtime.h>
#include <stdint.h>

typedef unsigned short u16;
typedef unsigned int u32;
using short8 = __attribute__((ext_vector_type(8))) short;   // 8 bf16
using f32x4  = __attribute__((ext_vector_type(4))) float;

#define BDIM 16
#define CDIM 512
#define KLAT 64
#define NTOK 4096

__device__ __forceinline__ u16 f2bf(float x) {
  union { float f; u32 u; } a; a.f = x;
  u32 r = a.u + 0x7FFFu + ((a.u >> 16) & 1u);   // RNE
  return (u16)(r >> 16);
}
__device__ __forceinline__ u32 pack2(float a, float b) {
  return (u32)f2bf(a) | ((u32)f2bf(b) << 16);
}
// order-preserving float->u32 key, and inverse+scale
__device__ __forceinline__ u32 f2key(float x) {
  u32 u = __float_as_uint(x);
  return (u & 0x80000000u) ? ~u : (u | 0x80000000u);
}
__device__ __forceinline__ float keyscale(u32 k_, u32 thr) {
  u32 u = (k_ & 0x80000000u) ? (k_ & 0x7FFFFFFFu) : ~k_;
  float v = __uint_as_float(u);
  return (k_ < thr) ? 0.75f * v : 1.25f * v;
}
// async 16B global->LDS copy (dest = wave-uniform base + lane*16)
__device__ __forceinline__ void gload_lds16(const void* g, void* l) {
  __builtin_amdgcn_global_load_lds(
      (const __attribute__((address_space(1))) unsigned int*)g,
      (__attribute__((address_space(3))) unsigned int*)l, 16, 0, 0);
}

// ---------------------------------------------------------------------------
// Setup: w0bf[k][c] = bf16(sum_o lin0[k][o]*conv1[o][c]); b0[k] = lin0[k]·conv1_b;
//        lin1bf[c][k] = bf16(lin1_w[c][k]) (direct cast, layout already K-contig);
//        cw_bf = bf16(conv2_w)
// ---------------------------------------------------------------------------
__global__ __launch_bounds__(256) void k_setup(
    const float* __restrict__ conv1_w, const float* __restrict__ conv1_b,
    const float* __restrict__ lin0_w,  const float* __restrict__ lin1_w,
    const float* __restrict__ conv2_w,
    u16* __restrict__ w0bf, float* __restrict__ b0,
    u16* __restrict__ lin1bf, u16* __restrict__ cwbf)
{
  const int bid = blockIdx.x;
  const int t = threadIdx.x;
  if (bid < 128) {
    // 16 k-blocks(4) x 8 c-blocks(64); lane=c (coalesced conv1 col), k wave-uniform
    const int kb = bid & 15, cb = bid >> 4;
    const int lane = t & 63;
    int k = kb * 4 + (t >> 6);
    k = __builtin_amdgcn_readfirstlane(k);
    const int c = cb * 64 + lane;
    float acc = 0.f;
    const float* l0 = lin0_w + (size_t)k * CDIM;   // scalar loads
    const float* cw = conv1_w + c;
#pragma unroll 4
    for (int o = 0; o < CDIM; ++o)
      acc = fmaf(l0[o], cw[(size_t)o * CDIM], acc);
    w0bf[k * CDIM + c] = f2bf(acc);
  } else if (bid == 128) {
    if (t < KLAT) {
      float acc = 0.f;
      for (int c = 0; c < CDIM; ++c) acc = fmaf(lin0_w[t * CDIM + c], conv1_b[c], acc);
      b0[t] = acc;
    }
  } else if (bid < 193) {
    // conv2_w -> bf16, 65536 float4 over 64 blocks
    const int b2 = bid - 129;
    const float4* src = (const float4*)conv2_w;
#pragma unroll
    for (int i = 0; i < 4; ++i) {
      int idx = (b2 * 256 + t) + i * 16384;
      float4 v = src[idx];
      uint2 o;
      o.x = pack2(v.x, v.y);
      o.y = pack2(v.z, v.w);
      *(uint2*)(cwbf + (size_t)idx * 4) = o;
    }
  } else {
    // lin1_w (512x64 f32, row-major = [c][k], k-contig) -> bf16; 4096 groups of 8
    const int b2 = bid - 193;                 // 0..3
#pragma unroll
    for (int i = 0; i < 4; ++i) {
      int g = b2 * 1024 + i * 256 + t;
      float4 v0 = *(const float4*)(lin1_w + (size_t)g * 8);
      float4 v1 = *(const float4*)(lin1_w + (size_t)g * 8 + 4);
      uint4 o;
      o.x = pack2(v0.x, v0.y); o.y = pack2(v0.z, v0.w);
      o.z = pack2(v1.x, v1.y); o.w = pack2(v1.z, v1.w);
      *(uint4*)(lin1bf + (size_t)g * 8) = o;
    }
  }
}

// ---------------------------------------------------------------------------
// K1 (fused transpose): logits[b][k][n] = sum_c w0[k][c]*x[c][n] + b0[k].
// Reads x[b][c][n] f32 directly; per kc-chunk stages a rotated 64c x 128n
// f32 tile in LDS, builds B-fragments by 8 scalar LDS reads + bf16 pack.
// ---------------------------------------------------------------------------
__global__ __launch_bounds__(256) void k_logits(
    const u16* __restrict__ w0bf, const float* __restrict__ x,
    const float* __restrict__ b0, float* __restrict__ logits)
{
  __shared__ u16 As[64 * 72];             // 9 KiB
  __shared__ float xt[64 * 128];          // 32 KiB rotated f32 tile (c-major)
  const int nb = blockIdx.x, b = blockIdx.y;
  const int t = threadIdx.x;
  const int wv = t >> 6, lane = t & 63;
  const int quad = lane >> 4, l15 = lane & 15;
  f32x4 acc[4][2];
#pragma unroll
  for (int mi = 0; mi < 4; ++mi)
#pragma unroll
    for (int ni = 0; ni < 2; ++ni) acc[mi][ni] = (f32x4){0.f, 0.f, 0.f, 0.f};

  for (int kc = 0; kc < 8; ++kc) {
#pragma unroll
    for (int i = 0; i < 2; ++i) {
      int ch = t + i * 256;               // 512 chunks of 8 bf16 (A: 64x64)
      int row = ch >> 3, col = (ch & 7) * 8;
      uint4 a = *(const uint4*)(w0bf + (size_t)row * CDIM + kc * 64 + col);
      *(uint4*)&As[row * 72 + col] = a;
    }
    // stage x chunk: 64 rows(c) x 32 col4(n); phys4 = (col4+row+(row>>3)) & 31
#pragma unroll
    for (int i = 0; i < 8; ++i) {
      int f4 = t + i * 256;               // 2048 float4
      int row = f4 >> 5, col4 = f4 & 31;
      float4 v = *(const float4*)(x + ((size_t)(b * CDIM + kc * 64 + row)) * NTOK
                                  + nb * 128 + col4 * 4);
      int phys4 = (col4 + row + (row >> 3)) & 31;
      *(float4*)&xt[row * 128 + phys4 * 4] = v;
    }
    __syncthreads();
#pragma unroll
    for (int kk = 0; kk < 2; ++kk) {
      short8 af[4], bf_[2];
#pragma unroll
      for (int mi = 0; mi < 4; ++mi)
        af[mi] = *(short8*)&As[(mi * 16 + l15) * 72 + kk * 32 + quad * 8];
#pragma unroll
      for (int ni = 0; ni < 2; ++ni) {
        const int n = wv * 32 + ni * 16 + l15;       // n_local 0..127
        const int n4 = n >> 2, ns = n & 3;
        union { u32 u[4]; short8 s; } cvt;
#pragma unroll
        for (int jj = 0; jj < 4; ++jj) {
          int ca = kk * 32 + quad * 8 + jj * 2;
          int cb2 = ca + 1;
          float v0 = xt[ca * 128 + (((n4 + ca + (ca >> 3)) & 31) * 4) + ns];
          float v1 = xt[cb2 * 128 + (((n4 + cb2 + (cb2 >> 3)) & 31) * 4) + ns];
          cvt.u[jj] = pack2(v0, v1);
        }
        bf_[ni] = cvt.s;
      }
#pragma unroll
      for (int mi = 0; mi < 4; ++mi)
#pragma unroll
        for (int ni = 0; ni < 2; ++ni)
          acc[mi][ni] = __builtin_amdgcn_mfma_f32_16x16x32_bf16(
              af[mi], bf_[ni], acc[mi][ni], 0, 0, 0);
    }
    __syncthreads();
  }
  // epilogue: + b0[k]   (C/D: col=lane&15, row=quad*4+reg)
#pragma unroll
  for (int mi = 0; mi < 4; ++mi) {
#pragma unroll
    for (int ni = 0; ni < 2; ++ni) {
#pragma unroll
      for (int r = 0; r < 4; ++r) {
        int row = mi * 16 + quad * 4 + r;            // latent k
        int col = nb * 128 + wv * 32 + ni * 16 + l15; // token n
        logits[((size_t)(b * KLAT + row)) * NTOK + col] = acc[mi][ni][r] + b0[row];
      }
    }
  }
}

// ---------------------------------------------------------------------------
// K2: in-place softmax over n (4096) per (b,k) row. 1024 blocks.
// ---------------------------------------------------------------------------
__global__ __launch_bounds__(256) void k_softmax(float* __restrict__ attn)
{
  __shared__ float red[4], red2[4];
  const int t = threadIdx.x;
  float* p = attn + (size_t)blockIdx.x * NTOK;
  float4 v[4];
#pragma unroll
  for (int i = 0; i < 4; ++i) v[i] = ((float4*)p)[t + i * 256];
  float m = v[0].x;
#pragma unroll
  for (int i = 0; i < 4; ++i)
    m = fmaxf(m, fmaxf(fmaxf(v[i].x, v[i].y), fmaxf(v[i].z, v[i].w)));
#pragma unroll
  for (int o = 1; o < 64; o <<= 1) m = fmaxf(m, __shfl_xor(m, o));
  const int wv = t >> 6, lane = t & 63;
  if (lane == 0) red[wv] = m;
  __syncthreads();
  m = fmaxf(fmaxf(red[0], red[1]), fmaxf(red[2], red[3]));
  float s = 0.f;
#pragma unroll
  for (int i = 0; i < 4; ++i) {
    v[i].x = __expf(v[i].x - m); s += v[i].x;
    v[i].y = __expf(v[i].y - m); s += v[i].y;
    v[i].z = __expf(v[i].z - m); s += v[i].z;
    v[i].w = __expf(v[i].w - m); s += v[i].w;
  }
#pragma unroll
  for (int o = 1; o < 64; o <<= 1) s += __shfl_xor(s, o);
  if (lane == 0) red2[wv] = s;
  __syncthreads();
  s = red2[0] + red2[1] + red2[2] + red2[3];
  const float inv = 1.f / s;
#pragma unroll
  for (int i = 0; i < 4; ++i) {
    v[i].x *= inv; v[i].y *= inv; v[i].z *= inv; v[i].w *= inv;
    ((float4*)p)[t + i * 256] = v[i];
  }
}

// ---------------------------------------------------------------------------
// K2b: attnT[b][n][k] = bf16( attn[b][k][n] / (1e-9 + sum_k attn[k][n]) ).
// ---------------------------------------------------------------------------
__global__ __launch_bounds__(256) void k_attnT(
    const float* __restrict__ attn, u16* __restrict__ attnT)
{
  __shared__ float tile[64 * 256];        // 64 KiB, phys4 = (col4 + row + (row>>3)) & 63
  __shared__ float inv_[256];
  const int n0 = blockIdx.x * 256, b = blockIdx.y;
  const int t = threadIdx.x;
#pragma unroll
  for (int i = 0; i < 16; ++i) {
    int f4 = t + i * 256;                 // 4096 float4 = 64 rows(k) x 64 col4(n)
    int row = f4 >> 6, col4 = f4 & 63;
    float4 v = *(const float4*)(attn + ((size_t)(b * KLAT + row)) * NTOK + n0 + col4 * 4);
    int phys4 = (col4 + row + (row >> 3)) & 63;
    *(float4*)&tile[row * 256 + phys4 * 4] = v;
  }
  __syncthreads();
  {
    // per-n column sum over 64 k; thread t owns n = t
    int n4 = t >> 2, sub = t & 3;
    float s = 0.f;
#pragma unroll
    for (int k = 0; k < 64; ++k) {
      int phys4 = (n4 + k + (k >> 3)) & 63;
      s += tile[k * 256 + phys4 * 4 + sub];
    }
    inv_[t] = 1.f / (1e-9f + s);
  }
  __syncthreads();
#pragma unroll
  for (int i = 0; i < 8; ++i) {
    int nr = (t >> 3) + i * 32;
    int cs = (t & 7) * 8;                 // 8 k-groups of 8
    float sc = inv_[nr];
    float w[8];
#pragma unroll
    for (int j = 0; j < 8; ++j) {
      int row = cs + j;
      int phys4 = ((nr >> 2) + row + (row >> 3)) & 63;
      w[j] = tile[row * 256 + phys4 * 4 + (nr & 3)] * sc;
    }
    uint4 o;
    o.x = pack2(w[0], w[1]); o.y = pack2(w[2], w[3]);
    o.z = pack2(w[4], w[5]); o.w = pack2(w[6], w[7]);
    *(uint4*)(attnT + ((size_t)(b * NTOK + n0 + nr)) * KLAT + cs) = o;
  }
}

// ---------------------------------------------------------------------------
// K3: fused lin1 + rank + transpose.  512 threads (8 waves), 64 KiB LDS.
// Phase 2: per-row SEQUENTIAL early-exit binary search (proven R3 form).
// ---------------------------------------------------------------------------
__global__ __launch_bounds__(512) void k_lin1rank(
    const u16* __restrict__ lin1bf, const u16* __restrict__ attnT,
    u16* __restrict__ yrt)
{
  __shared__ float tile[32 * 512];        // 64 KiB rotated tile (k_rank layout)
  const int n0 = blockIdx.x * 512, c0 = blockIdx.y * 32, b = blockIdx.z;
  const int t = threadIdx.x;
  const int wv = t >> 6, lane = t & 63;   // wv 0..7
  const int quad = lane >> 4, l15 = lane & 15;

  // ---- phase 1: MFMA  (wave wv owns n-cols [wv*64, +64), all 32 c)
  short8 af[2][2], bfr[4][2];
#pragma unroll
  for (int mi = 0; mi < 2; ++mi)
#pragma unroll
    for (int kk = 0; kk < 2; ++kk)
      af[mi][kk] = *(const short8*)(lin1bf +
          (size_t)(c0 + mi * 16 + l15) * KLAT + kk * 32 + quad * 8);
#pragma unroll
  for (int ni = 0; ni < 4; ++ni)
#pragma unroll
    for (int kk = 0; kk < 2; ++kk)
      bfr[ni][kk] = *(const short8*)(attnT +
          ((size_t)(b * NTOK + n0 + wv * 64 + ni * 16 + l15)) * KLAT + kk * 32 + quad * 8);
  f32x4 acc[2][4];
#pragma unroll
  for (int mi = 0; mi < 2; ++mi)
#pragma unroll
    for (int ni = 0; ni < 4; ++ni) acc[mi][ni] = (f32x4){0.f, 0.f, 0.f, 0.f};
#pragma unroll
  for (int kk = 0; kk < 2; ++kk)
#pragma unroll
    for (int mi = 0; mi < 2; ++mi)
#pragma unroll
      for (int ni = 0; ni < 4; ++ni)
        acc[mi][ni] = __builtin_amdgcn_mfma_f32_16x16x32_bf16(
            af[mi][kk], bfr[ni][kk], acc[mi][ni], 0, 0, 0);
  // acc -> rotated LDS tile (C/D: col=l15 -> n, row=quad*4+r -> c)
#pragma unroll
  for (int mi = 0; mi < 2; ++mi) {
#pragma unroll
    for (int ni = 0; ni < 4; ++ni) {
#pragma unroll
      for (int r = 0; r < 4; ++r) {
        int row = mi * 16 + quad * 4 + r;             // c_local 0..31
        int col = wv * 64 + ni * 16 + l15;            // n_local 0..511
        int phys4 = ((col >> 2) + row + (row >> 3)) & 127;
        tile[row * 512 + phys4 * 4 + (col & 3)] = acc[mi][ni][r];
      }
    }
  }
  __syncthreads();

  // ---- phase 2: rank. wave wv owns rows [wv*4, +4); sequential per row.
#pragma unroll
  for (int r = 0; r < 4; ++r) {
    const int row = wv * 4 + r;
    const int rot = row + (row >> 3);
    const int c4a = (lane + rot) & 127;          // logical col4 = lane
    const int c4b = (64 + lane + rot) & 127;     // logical col4 = 64 + lane
    float* pa = &tile[row * 512 + c4a * 4];
    float* pb = &tile[row * 512 + c4b * 4];
    float4 va = *(const float4*)pa;
    float4 vb = *(const float4*)pb;
    u32 key[8];
    key[0] = f2key(va.x); key[1] = f2key(va.y);
    key[2] = f2key(va.z); key[3] = f2key(va.w);
    key[4] = f2key(vb.x); key[5] = f2key(vb.y);
    key[6] = f2key(vb.z); key[7] = f2key(vb.w);
    // seed [lo,hi] with the row's key range (butterfly min/max)
    u32 kmin = key[0], kmax = key[0];
#pragma unroll
    for (int j = 1; j < 8; ++j) {
      kmin = key[j] < kmin ? key[j] : kmin;
      kmax = key[j] > kmax ? key[j] : kmax;
    }
#pragma unroll
    for (int o = 1; o < 64; o <<= 1) {
      u32 a_ = __shfl_xor(kmin, o), b_ = __shfl_xor(kmax, o);
      kmin = a_ < kmin ? a_ : kmin;
      kmax = b_ > kmax ? b_ : kmax;
    }
    // early-exit binary search: exact 256th-largest classification
    u32 lo = kmin, hi = kmax;
    u32 thr;
    if (lo >= hi) thr = lo;
    else for (;;) {
      u32 d = hi - lo;
      u32 mid = lo + (d >> 1) + (d & 1u);
      int cnt = 0;
#pragma unroll
      for (int j = 0; j < 8; ++j)
        cnt += (int)__popcll(__ballot(key[j] >= mid));
      if (cnt == 256) { thr = mid; break; }   // mid in (v257, v256]: exact classes
      if (cnt > 256) lo = mid; else hi = mid - 1u;
      if (lo >= hi) { thr = lo; break; }      // exact v256 (duplicate-safe)
    }
    float4 oa, ob;
    oa.x = keyscale(key[0], thr); oa.y = keyscale(key[1], thr);
    oa.z = keyscale(key[2], thr); oa.w = keyscale(key[3], thr);
    ob.x = keyscale(key[4], thr); ob.y = keyscale(key[5], thr);
    ob.z = keyscale(key[6], thr); ob.w = keyscale(key[7], thr);
    *(float4*)pa = oa;
    *(float4*)pb = ob;
  }
  __syncthreads();

  // ---- phase 3: transposed bf16 write yrt[b][n][c]  (512 threads, 4 iters)
#pragma unroll
  for (int i = 0; i < 4; ++i) {
    int nr = (t >> 2) + i * 128;
    int cs = (t & 3) * 8;
    float w[8];
#pragma unroll
    for (int j = 0; j < 8; ++j) {
      int row = cs + j;
      int phys4 = ((nr >> 2) + row + (row >> 3)) & 127;
      w[j] = tile[row * 512 + phys4 * 4 + (nr & 3)];
    }
    uint4 o;
    o.x = pack2(w[0], w[1]); o.y = pack2(w[2], w[3]);
    o.z = pack2(w[4], w[5]); o.w = pack2(w[6], w[7]);
    *(uint4*)(yrt + ((size_t)(b * NTOK + n0 + nr)) * CDIM + c0 + cs) = o;
  }
}

// ---------------------------------------------------------------------------
// K5: out = relu(relu(conv2_w @ yr) + x).  bf16 MFMA 16x16x32, 128x128 tile,
// BK=64, 4 waves each 64x64.  Staging via global_load_lds (16B) into LINEAR
// 128B rows with XOR-granule swizzle (0 bank conflicts measured).
// Epilogue: LDS-staged (reuses As/Bs as 32x132 f32 buffer) -> fully
// coalesced float4 x-load + out-store (was 128 scalar VMEM/thread).
// ---------------------------------------------------------------------------
__global__ __launch_bounds__(256) void k_conv2(
    const u16* __restrict__ cwbf, const u16* __restrict__ yrt,
    const float* __restrict__ x, float* __restrict__ out)
{
  __shared__ __align__(16) u16 smem[2 * 128 * 64];   // 32 KiB total
  u16* As = smem;                                    // 16 KiB linear swizzled rows
  u16* Bs = smem + 128 * 64;                         // 16 KiB
  float* sbuf = (float*)smem;                        // epilogue reuse: 32x132 f32 (16.9 KiB)
  const int nb = blockIdx.x, mb = blockIdx.y, b = blockIdx.z;
  const int t = threadIdx.x;
  const int wv = t >> 6, lane = t & 63;
  const int wm = wv >> 1, wn = wv & 1;
  const int quad = lane >> 4, l15 = lane & 15;
  const int lrow = lane >> 3, lg = lane & 7;   // staging: lane -> (row-in-8, granule)
  f32x4 acc[4][4];
#pragma unroll
  for (int mi = 0; mi < 4; ++mi)
#pragma unroll
    for (int ni = 0; ni < 4; ++ni) acc[mi][ni] = (f32x4){0.f, 0.f, 0.f, 0.f};

  for (int kc = 0; kc < 8; ++kc) {
#pragma unroll
    for (int i = 0; i < 4; ++i) {
      const int r0 = i * 32 + wv * 8;           // wave-uniform row base (8 rows/call)
      const int row = r0 + lrow;
      const int gsrc = lg ^ (row & 7);          // inverse-swizzled source granule
      const u16* ga = cwbf + ((size_t)(mb * 128 + row)) * CDIM + kc * 64 + gsrc * 8;
      gload_lds16(ga, &As[r0 * 64]);
      const u16* gb = yrt + ((size_t)(b * NTOK + nb * 128 + row)) * CDIM + kc * 64 + gsrc * 8;
      gload_lds16(gb, &Bs[r0 * 64]);
    }
    __syncthreads();
#pragma unroll
    for (int kk = 0; kk < 2; ++kk) {
      short8 af[4], bf_[4];
#pragma unroll
      for (int mi = 0; mi < 4; ++mi) {
        int row = wm * 64 + mi * 16 + l15;
        int q = kk * 4 + quad;
        af[mi] = *(short8*)&As[row * 64 + ((q ^ (row & 7)) * 8)];
      }
#pragma unroll
      for (int ni = 0; ni < 4; ++ni) {
        int row = wn * 64 + ni * 16 + l15;
        int q = kk * 4 + quad;
        bf_[ni] = *(short8*)&Bs[row * 64 + ((q ^ (row & 7)) * 8)];
      }
#pragma unroll
      for (int mi = 0; mi < 4; ++mi)
#pragma unroll
        for (int ni = 0; ni < 4; ++ni)
          acc[mi][ni] = __builtin_amdgcn_mfma_f32_16x16x32_bf16(
              af[mi], bf_[ni], acc[mi][ni], 0, 0, 0);
    }
    __syncthreads();
  }
  // epilogue: per mi, stage 32x128 f32 (rows {wm*64+mi*16..+16} x both wn)
  // into sbuf (pitch 132: writes 2-way banked = free, reads float4-clean),
  // then coalesced float4 RMW: relu(acc) + x -> relu -> out.
#pragma unroll
  for (int mi = 0; mi < 4; ++mi) {
#pragma unroll
    for (int ni = 0; ni < 4; ++ni)
#pragma unroll
      for (int r = 0; r < 4; ++r)
        sbuf[(wm * 16 + quad * 4 + r) * 132 + wn * 64 + ni * 16 + l15] = acc[mi][ni][r];
    __syncthreads();
#pragma unroll
    for (int i = 0; i < 4; ++i) {
      int f4 = t + i * 256;                 // 1024 float4 = 32 rows x 32 col4
      int sr = f4 >> 5, sc4 = f4 & 31;
      int grow = mb * 128 + (sr >> 4) * 64 + mi * 16 + (sr & 15);
      size_t off = ((size_t)(b * CDIM + grow)) * NTOK + nb * 128 + sc4 * 4;
      float4 a4 = *(const float4*)&sbuf[sr * 132 + sc4 * 4];
      float4 xa = *(const float4*)(x + off);
      float4 o4;
      o4.x = fmaxf(fmaxf(a4.x, 0.f) + xa.x, 0.f);
      o4.y = fmaxf(fmaxf(a4.y, 0.f) + xa.y, 0.f);
      o4.z = fmaxf(fmaxf(a4.z, 0.f) + xa.z, 0.f);
      o4.w = fmaxf(fmaxf(a4.w, 0.f) + xa.w, 0.f);
      *(float4*)(out + off) = o4;
    }
    __syncthreads();
  }
}

// ---------------------------------------------------------------------------
extern "C" void kernel_launch(void* const* d_in, const int* in_sizes, int n_in,
                              void* d_out, int out_size, void* d_ws, size_t ws_size,
                              hipStream_t stream)
{
  const float* x       = (const float*)d_in[0];
  const float* conv1_w = (const float*)d_in[1];
  const float* conv1_b = (const float*)d_in[2];
  const float* lin0_w  = (const float*)d_in[3];
  const float* lin1_w  = (const float*)d_in[4];
  const float* conv2_w = (const float*)d_in[5];
  float* out = (float*)d_out;

  char* ws = (char*)d_ws;
  float* attn  = (float*)ws;                               // 16,777,216 B
  u16*   yrt   = (u16*)(ws + 16777216);                    // 67,108,864 B (k_lin1rank -> k_conv2)
  u16*   attnT = (u16*)d_out;                              // 8,388,608 B in d_out (free until
                                                           // k_conv2 writes out) -- must NOT
                                                           // alias yrt (read+write in k_lin1rank)
  char*  wsm   = ws + 16777216 + 67108864;
  u16*   w0bf  = (u16*)wsm;                                // 65,536 B (slot 131072)
  float* b0    = (float*)(wsm + 131072);                   // 256 B
  u16*   lin1bf= (u16*)(wsm + 131328);                     // 65,536 B (slot 131072)
  u16*   cwbf  = (u16*)(wsm + 262400);                     // 524,288 B

  k_setup   <<<197, 256, 0, stream>>>(conv1_w, conv1_b, lin0_w, lin1_w, conv2_w,
                                      w0bf, b0, lin1bf, cwbf);
  k_logits  <<<dim3(32, 16), 256, 0, stream>>>(w0bf, x, b0, attn);
  k_softmax <<<1024, 256, 0, stream>>>(attn);
  k_attnT   <<<dim3(16, 16), 256, 0, stream>>>(attn, attnT);
  k_lin1rank<<<dim3(8, 16, 16), 512, 0, stream>>>(lin1bf, attnT, yrt);
  k_conv2   <<<dim3(32, 4, 16), 256, 0, stream>>>(cwbf, yrt, x, out);
}